// Round 16
// baseline (128.558 us; speedup 1.0000x reference)
//
#include <hip/hip_runtime.h>
#include <hip/hip_bf16.h>

typedef __attribute__((ext_vector_type(8))) __bf16 bf16x8;
typedef __attribute__((ext_vector_type(4))) float f32x4;

#define MFMA16(a,b,c) __builtin_amdgcn_mfma_f32_16x16x32_bf16(a,b,c,0,0,0)

__device__ __forceinline__ unsigned short f2b(float x){
  __hip_bfloat16 h = __float2bfloat16(x);
  return __builtin_bit_cast(unsigned short, h);
}

// async global->LDS, 16B per lane. LDS dest is wave-uniform base + lane*16.
__device__ __forceinline__ void gload16(const unsigned short* g, unsigned short* l){
  __builtin_amdgcn_global_load_lds(
      (const __attribute__((address_space(1))) unsigned int*)g,
      (__attribute__((address_space(3))) unsigned int*)l, 16, 0, 0);
}

// ---------------- Fused prep: rope table + X cvt + Wqkv transpose -----------
__global__ __launch_bounds__(256) void k_prep(
    const float* __restrict__ X,  const float* __restrict__ Wq,
    const float* __restrict__ Wk, const float* __restrict__ Wv,
    float* __restrict__ ct, float* __restrict__ st,
    unsigned short* __restrict__ Xb, unsigned short* __restrict__ Wt)
{
  __shared__ float t[32][33];
  int bid = blockIdx.x;
  if (bid < 128){                       // rope cos/sin table
    int i = bid*256 + threadIdx.x;
    int tt = i >> 5, f = i & 31;
    float freq = powf(10000.0f, -(float)f/32.0f);
    float a = (float)tt * freq;
    ct[i] = cosf(a); st[i] = sinf(a);
    return;
  }
  bid -= 128;
  if (bid < 1024){                      // X fp32 -> bf16
    const int n4 = 2048*2048/4;
    for (int i = bid*256 + threadIdx.x; i < n4; i += 1024*256){
      float4 v = ((const float4*)X)[i];
      ushort4 o; o.x=f2b(v.x); o.y=f2b(v.y); o.z=f2b(v.z); o.w=f2b(v.w);
      ((ushort4*)Xb)[i] = o;
    }
    return;
  }
  bid -= 1024;
  {                                     // W[K][N] -> Wt[N][K] (Q|K|V fused)
    int bx = bid % 96, by = bid / 96;
    int n0 = bx*32, k0 = by*32;
    const float* src; int N, nl;
    if (n0 < 2048)      { src=Wq; N=2048; nl=n0; }
    else if (n0 < 2560) { src=Wk; N=512;  nl=n0-2048; }
    else                { src=Wv; N=512;  nl=n0-2560; }
    int r = threadIdx.x>>5, c = threadIdx.x&31;
    #pragma unroll
    for (int it=0; it<4; ++it)
      t[r+8*it][c] = src[(size_t)(k0+r+8*it)*N + nl + c];
    __syncthreads();
    #pragma unroll
    for (int it=0; it<4; ++it)
      Wt[(size_t)(n0+r+8*it)*2048 + k0 + c] = f2b(t[c][r+8*it]);
  }
}

// ---------------- QKV GEMM: 64x64 tile, BK=32, 3-buffer vmcnt(2) ------------
// grid 1536 (32 mt x 48 nt) = 6 blocks/CU, 24 waves/CU. XCD x owns n-tiles
// [6x,6x+6) -> weight slice 1.5MB L2-resident. Wave grid 2x2, each 32x32.
// q pre-scaled by 0.125*log2(e); v written transposed.
__global__ __launch_bounds__(256) void k_qkv(
    const unsigned short* __restrict__ A, const unsigned short* __restrict__ Bt,
    const float* __restrict__ ct, const float* __restrict__ st,
    unsigned short* __restrict__ qb, unsigned short* __restrict__ kb,
    unsigned short* __restrict__ vt)
{
  __shared__ unsigned short As[3][64*32];
  __shared__ unsigned short Bs[3][64*32];
  const int xcd = blockIdx.x & 7, idx = blockIdx.x >> 3;   // idx 0..191
  const int mt = idx & 31;
  const int nt = xcd*6 + (idx >> 5);    // 0..47
  const int bm = mt*64, bn_g = nt*64;
  const int tid=threadIdx.x, wave=tid>>6, lane=tid&63;
  const int lrow=lane&15, kgrp=lane>>4;
  const int wm=(wave>>1)*32, wn=(wave&1)*32;
  const int arow = tid>>2;
  const int acs  = (((tid&3) ^ ((tid>>3)&3)))*8;   // pre-swizzled global 16B-slot
  const int ksw  = (kgrp ^ ((lrow>>1)&3))*8;       // swizzled read slot
  f32x4 acc[2][2] = {};

  #define STAGE_Q(buf, k0) do {                                                               \
    gload16(&A [(size_t)(bm + arow)*2048 + (k0) + acs], &As[buf][(wave*64)*8]);               \
    gload16(&Bt[(size_t)(bn_g + arow)*2048 + (k0) + acs], &Bs[buf][(wave*64)*8]);             \
  } while(0)

  #define COMPUTE_Q(buf) do {                                          \
    bf16x8 a0,a1,b0,b1;                                                \
    a0 = *(const bf16x8*)&As[buf][(wm+ 0+lrow)*32 + ksw];              \
    a1 = *(const bf16x8*)&As[buf][(wm+16+lrow)*32 + ksw];              \
    b0 = *(const bf16x8*)&Bs[buf][(wn+ 0+lrow)*32 + ksw];              \
    b1 = *(const bf16x8*)&Bs[buf][(wn+16+lrow)*32 + ksw];              \
    acc[0][0]=MFMA16(a0,b0,acc[0][0]); acc[0][1]=MFMA16(a0,b1,acc[0][1]); \
    acc[1][0]=MFMA16(a1,b0,acc[1][0]); acc[1][1]=MFMA16(a1,b1,acc[1][1]); \
  } while(0)

  STAGE_Q(0, 0);
  STAGE_Q(1, 32);
  int cur = 0;
  #pragma unroll 1
  for (int t=0; t<64; ++t){
    asm volatile("s_waitcnt vmcnt(2)" ::: "memory");
    __builtin_amdgcn_s_barrier();
    int kn = t+2; if (kn > 63) kn = 63;          // clamped dup loads at tail (unused)
    int nb = cur+2; if (nb > 2) nb -= 3;
    STAGE_Q(nb, kn*32);
    COMPUTE_Q(cur);
    cur = (cur==2) ? 0 : cur+1;
  }

  const int wtype = (bn_g < 2048) ? 0 : (bn_g < 2560 ? 1 : 2);
  const float qscale = 0.125f * 1.44269504f;   // 1/sqrt(D) * log2(e)
  #pragma unroll
  for (int mi=0;mi<2;mi++){
    #pragma unroll
    for (int ni=0;ni<2;ni++){
      int gr0 = bm + wm + mi*16 + kgrp*4;
      int gc  = bn_g + wn + ni*16 + lrow;
      if (wtype==2){
        int c = gc - 2560;                 // d_global in [0,512)
        int bq = gr0 >> 10, s0 = gr0 & 1023;
        ushort4 o;
        o.x=f2b(acc[mi][ni][0]); o.y=f2b(acc[mi][ni][1]);
        o.z=f2b(acc[mi][ni][2]); o.w=f2b(acc[mi][ni][3]);
        *(ushort4*)&vt[((size_t)(bq*512 + c))*1024 + s0] = o;
      } else {
        int d = gc & 63, fi = d >> 1, odd = d & 1;
        #pragma unroll
        for (int r=0;r<4;r++){
          float x = acc[mi][ni][r];
          float p = __shfl_xor(x, 1, 64);
          int srow = (gr0 + r) & 1023;
          float c = ct[srow*32 + fi], sn = st[srow*32 + fi];
          float o = odd ? (x*c + p*sn) : (x*c - p*sn);
          if (wtype==0) qb[(size_t)(gr0+r)*2048 + gc] = f2b(o*qscale);
          else          kb[(size_t)(gr0+r)*512 + (gc-2048)] = f2b(o);
        }
      }
    }
  }
  #undef STAGE_Q
  #undef COMPUTE_Q
}

// ---------------- Flash attention (GQA, causal) + fused Wo transpose --------
#define LDP 72   // 144B row pitch: 16B-aligned; b128 reads uniform 8/bank
__global__ __launch_bounds__(256) void k_attn(
    const unsigned short* __restrict__ qb, const unsigned short* __restrict__ kb,
    const unsigned short* __restrict__ vt, unsigned short* __restrict__ ctxb,
    const float* __restrict__ Wo, unsigned short* __restrict__ Wot)
{
  __shared__ unsigned short Ks[2][64*LDP];
  __shared__ unsigned short Vs[2][64*LDP];   // V^T rows: [d][kv]
  __shared__ unsigned short QP[64*LDP];      // Q tile, then per-wave P [q][kv]

  if (blockIdx.x >= 512){                    // ---- Wo transpose rider ----
    __shared__ float t[32][33];
    int bid = blockIdx.x - 512;
    int n0 = (bid & 63)*32, k0 = (bid >> 6)*32;
    int r = threadIdx.x>>5, c = threadIdx.x&31;
    #pragma unroll
    for (int it=0; it<4; ++it)
      t[r+8*it][c] = Wo[(size_t)(k0+r+8*it)*2048 + n0 + c];
    __syncthreads();
    #pragma unroll
    for (int it=0; it<4; ++it)
      Wot[(size_t)(n0+r+8*it)*2048 + k0 + c] = f2b(t[c][r+8*it]);
    return;
  }

  const int kvh = blockIdx.x & 7;
  const int s   = blockIdx.x >> 3;           // 0..63
  const int b   = s >> 5;
  const int hh  = (s >> 3) & 3;
  const int p   = s & 7;
  const int h   = kvh*4 + hh;

  const int tid=threadIdx.x, wave=tid>>6, lane=tid&63;
  const int lrow=lane&15, kgrp=lane>>4;
  const int wq = wave*16;
  const int sr = tid>>2, seg = (tid&3)*16;

  const unsigned short* kbase = kb + (size_t)(b*1024)*512 + kvh*64 + seg;
  const unsigned short* vbase = vt + ((size_t)(b*512 + kvh*64 + sr))*1024 + seg;

  #pragma unroll
  for (int phase=0; phase<2; ++phase){
    const int qt = phase==0 ? 15-p : p;
    const int q0 = qt*64;

    __syncthreads();   // all waves done with previous phase's LDS
    { // stage Q tile 64x64 + KV tile j=0 into buf 0
      const unsigned short* src = qb + (size_t)(b*1024 + q0 + sr)*2048 + h*64 + seg;
      *(uint4*)&QP[sr*LDP + seg]     = *(const uint4*)&src[0];
      *(uint4*)&QP[sr*LDP + seg + 8] = *(const uint4*)&src[8];
      const unsigned short* ksrc = kbase + (size_t)sr*512;
      *(uint4*)&Ks[0][sr*LDP + seg]     = *(const uint4*)&ksrc[0];
      *(uint4*)&Ks[0][sr*LDP + seg + 8] = *(const uint4*)&ksrc[8];
      *(uint4*)&Vs[0][sr*LDP + seg]     = *(const uint4*)&vbase[0];
      *(uint4*)&Vs[0][sr*LDP + seg + 8] = *(const uint4*)&vbase[8];
    }
    __syncthreads();

    bf16x8 qa[2];
    #pragma unroll
    for (int ks=0;ks<2;ks++)
      qa[ks] = *(const bf16x8*)&QP[(wq+lrow)*LDP + ks*32 + kgrp*8];

    float m_run = -1e30f, l_run = 0.f;
    f32x4 out[4] = {};

    for (int j=0;j<=qt;j++){
      const int cb = j&1;
      uint4 kra, krb, vra, vrb;
      if (j < qt){   // T14: issue next tile's loads; latency hides under compute
        const unsigned short* ksrc = kbase + (size_t)((j+1)*64 + sr)*512;
        kra = *(const uint4*)&ksrc[0]; krb = *(const uint4*)&ksrc[8];
        const unsigned short* vsrc = vbase + (j+1)*64;
        vra = *(const uint4*)&vsrc[0]; vrb = *(const uint4*)&vsrc[8];
      }

      // S^T = K·Q^T (exp2 domain): sc[ni][r] = S[q=wq+lrow][kv=ni*16+kgrp*4+r]
      f32x4 sc[4] = {};
      __builtin_amdgcn_s_setprio(1);
      #pragma unroll
      for (int ks=0;ks<2;ks++){
        #pragma unroll
        for (int ni=0;ni<4;ni++){
          bf16x8 kf = *(const bf16x8*)&Ks[cb][(ni*16+lrow)*LDP + ks*32 + kgrp*8];
          sc[ni] = MFMA16(kf, qa[ks], sc[ni]);
        }
      }
      __builtin_amdgcn_s_setprio(0);

      if (j == qt){   // causal mask: kv_local > q_local
        #pragma unroll
        for (int ni=0;ni<4;ni++)
          #pragma unroll
          for (int r=0;r<4;r++)
            if (ni*16 + kgrp*4 + r > wq + lrow) sc[ni][r] = -1e30f;
      }

      // online softmax: in-lane over 16 scores, + 2 shfl across sibling lanes.
      float mx = sc[0][0];
      #pragma unroll
      for (int ni=0;ni<4;ni++)
        #pragma unroll
        for (int r=0;r<4;r++) mx = fmaxf(mx, sc[ni][r]);
      mx = fmaxf(mx, __shfl_xor(mx, 16, 64));
      mx = fmaxf(mx, __shfl_xor(mx, 32, 64));
      // defer-max (T13): only rescale when max grew by >12 (log2 domain)
      if (__any(mx > m_run + 12.0f)){
        float mnew = fmaxf(m_run, mx);
        float corr = exp2f(m_run - mnew);
        m_run = mnew;
        l_run *= corr;
        #pragma unroll
        for (int di=0;di<4;di++)
          #pragma unroll
          for (int r=0;r<4;r++) out[di][r] *= corr;
      }
      float rsum = 0.f;
      #pragma unroll
      for (int ni=0;ni<4;ni++)
        #pragma unroll
        for (int r=0;r<4;r++){
          float pv = exp2f(sc[ni][r] - m_run);
          sc[ni][r] = pv;
          rsum += pv;
        }
      rsum += __shfl_xor(rsum, 16, 64);
      rsum += __shfl_xor(rsum, 32, 64);
      l_run += rsum;

      // P[q][kv] -> wave-private QP rows; 4x b64 writes (no barrier needed)
      #pragma unroll
      for (int ni=0;ni<4;ni++){
        ushort4 o;
        o.x=f2b(sc[ni][0]); o.y=f2b(sc[ni][1]);
        o.z=f2b(sc[ni][2]); o.w=f2b(sc[ni][3]);
        *(ushort4*)&QP[(wq+lrow)*LDP + ni*16 + kgrp*4] = o;
      }

      // O^T += V^T · P
      __builtin_amdgcn_s_setprio(1);
      #pragma unroll
      for (int ks2=0;ks2<2;ks2++){
        bf16x8 pb = *(const bf16x8*)&QP[(wq+lrow)*LDP + ks2*32 + kgrp*8];
        #pragma unroll
        for (int di=0;di<4;di++){
          bf16x8 vf = *(const bf16x8*)&Vs[cb][(di*16+lrow)*LDP + ks2*32 + kgrp*8];
          out[di] = MFMA16(vf, pb, out[di]);
        }
      }
      __builtin_amdgcn_s_setprio(0);

      if (j < qt){   // write next tile into buf (j+1)&1
        const int nb = (j+1)&1;
        *(uint4*)&Ks[nb][sr*LDP + seg]     = kra;
        *(uint4*)&Ks[nb][sr*LDP + seg + 8] = krb;
        *(uint4*)&Vs[nb][sr*LDP + seg]     = vra;
        *(uint4*)&Vs[nb][sr*LDP + seg + 8] = vrb;
      }
      __syncthreads();
    }

    // out[di][r] = O[q = wq+lrow][d = di*16+kgrp*4+r] -> 4x ushort4 stores
    float rl = 1.0f / l_run;
    #pragma unroll
    for (int di=0;di<4;di++){
      ushort4 o;
      o.x=f2b(out[di][0]*rl); o.y=f2b(out[di][1]*rl);
      o.z=f2b(out[di][2]*rl); o.w=f2b(out[di][3]*rl);
      *(ushort4*)&ctxb[(size_t)(b*1024 + q0 + wq + lrow)*2048
                       + h*64 + di*16 + kgrp*4] = o;
    }
  }
}

// ---------------- Output projection: 64x64 tile, BK=32, 3-buffer vmcnt(2) ---
// grid 1024 (32 mt x 32 nt) = 4 blocks/CU, 16 waves/CU. XCD x owns n-tiles
// [4x,4x+4) -> Wot slice 1MB in L2. Wave grid 2x2, each wave 32x32.
__global__ __launch_bounds__(256) void k_oproj(
    const unsigned short* __restrict__ A, const unsigned short* __restrict__ Bt,
    float* __restrict__ out)
{
  __shared__ unsigned short As[3][64*32];
  __shared__ unsigned short Bs[3][64*32];
  const int xcd = blockIdx.x & 7, idx = blockIdx.x >> 3;   // idx 0..127
  const int mt = idx & 31;
  const int nt = xcd*4 + (idx >> 5);    // 0..31
  const int bm = mt*64, bn = nt*64;
  const int tid=threadIdx.x, wave=tid>>6, lane=tid&63;
  const int lrow=lane&15, kgrp=lane>>4;
  const int wm=(wave>>1)*32, wn=(wave&1)*32;
  const int arow = tid>>2;
  const int acs  = (((tid&3) ^ ((tid>>3)&3)))*8;
  const int ksw  = (kgrp ^ ((lrow>>1)&3))*8;
  f32x4 acc[2][2] = {};

  #define STAGE_O(buf, k0) do {                                                               \
    gload16(&A [(size_t)(bm + arow)*2048 + (k0) + acs], &As[buf][(wave*64)*8]);               \
    gload16(&Bt[(size_t)(bn + arow)*2048 + (k0) + acs], &Bs[buf][(wave*64)*8]);               \
  } while(0)

  #define COMPUTE_O(buf) do {                                          \
    bf16x8 a0,a1,b0,b1;                                                \
    a0 = *(const bf16x8*)&As[buf][(wm+ 0+lrow)*32 + ksw];              \
    a1 = *(const bf16x8*)&As[buf][(wm+16+lrow)*32 + ksw];              \
    b0 = *(const bf16x8*)&Bs[buf][(wn+ 0+lrow)*32 + ksw];              \
    b1 = *(const bf16x8*)&Bs[buf][(wn+16+lrow)*32 + ksw];              \
    acc[0][0]=MFMA16(a0,b0,acc[0][0]); acc[0][1]=MFMA16(a0,b1,acc[0][1]); \
    acc[1][0]=MFMA16(a1,b0,acc[1][0]); acc[1][1]=MFMA16(a1,b1,acc[1][1]); \
  } while(0)

  STAGE_O(0, 0);
  STAGE_O(1, 32);
  int cur = 0;
  #pragma unroll 1
  for (int t=0; t<64; ++t){
    asm volatile("s_waitcnt vmcnt(2)" ::: "memory");
    __builtin_amdgcn_s_barrier();
    int kn = t+2; if (kn > 63) kn = 63;
    int nb = cur+2; if (nb > 2) nb -= 3;
    STAGE_O(nb, kn*32);
    COMPUTE_O(cur);
    cur = (cur==2) ? 0 : cur+1;
  }

  #pragma unroll
  for (int mi=0;mi<2;mi++)
    #pragma unroll
    for (int ni=0;ni<2;ni++){
      int gr0 = bm + wm + mi*16 + kgrp*4;
      int gc  = bn + wn + ni*16 + lrow;
      #pragma unroll
      for (int r=0;r<4;r++)
        out[(size_t)(gr0+r)*2048 + gc] = acc[mi][ni][r];
    }
  #undef STAGE_O
  #undef COMPUTE_O
}

// ---------------- launch ----------------------------------------------------
extern "C" void kernel_launch(void* const* d_in, const int* in_sizes, int n_in,
                              void* d_out, int out_size, void* d_ws, size_t ws_size,
                              hipStream_t stream)
{
  const float* X  = (const float*)d_in[0];
  const float* Wq = (const float*)d_in[1];
  const float* Wk = (const float*)d_in[2];
  const float* Wv = (const float*)d_in[3];
  const float* Wo = (const float*)d_in[4];
  float* out = (float*)d_out;
  char* ws = (char*)d_ws;

  const size_t MB = 1048576;
  float* ct = (float*)ws;                                   // 128 KB
  float* st = (float*)(ws + 128*1024);                      // 128 KB
  unsigned short* Xb   = (unsigned short*)(ws + 256*1024);            // 8 MB
  unsigned short* Wt   = (unsigned short*)(ws + 256*1024 + 8*MB);     // 12 MB
  unsigned short* Wot  = (unsigned short*)(ws + 256*1024 + 20*MB);    // 8 MB
  unsigned short* qb   = (unsigned short*)(ws + 256*1024 + 28*MB);    // 8 MB
  unsigned short* kb   = (unsigned short*)(ws + 256*1024 + 36*MB);    // 2 MB
  unsigned short* vt   = (unsigned short*)(ws + 256*1024 + 38*MB);    // 2 MB (V^T)
  unsigned short* ctxb = (unsigned short*)(ws + 256*1024 + 40*MB);    // 8 MB

  hipLaunchKernelGGL(k_prep, dim3(7296), dim3(256), 0, stream,
                     X, Wq, Wk, Wv, ct, st, Xb, Wt);
  hipLaunchKernelGGL(k_qkv, dim3(1536), dim3(256), 0, stream,
                     Xb, Wt, ct, st, qb, kb, vt);
  hipLaunchKernelGGL(k_attn, dim3(4608), dim3(256), 0, stream,
                     qb, kb, vt, ctxb, Wo, Wot);
  hipLaunchKernelGGL(k_oproj, dim3(1024), dim3(256), 0, stream, ctxb, Wot, out);
}

// Round 17
// 125.519 us; speedup vs baseline: 1.0242x; 1.0242x over previous
//
#include <hip/hip_runtime.h>
#include <hip/hip_bf16.h>

typedef __attribute__((ext_vector_type(8))) __bf16 bf16x8;
typedef __attribute__((ext_vector_type(4))) float f32x4;

#define MFMA16(a,b,c) __builtin_amdgcn_mfma_f32_16x16x32_bf16(a,b,c,0,0,0)

__device__ __forceinline__ unsigned short f2b(float x){
  __hip_bfloat16 h = __float2bfloat16(x);
  return __builtin_bit_cast(unsigned short, h);
}

// async global->LDS, 16B per lane. LDS dest is wave-uniform base + lane*16.
__device__ __forceinline__ void gload16(const unsigned short* g, unsigned short* l){
  __builtin_amdgcn_global_load_lds(
      (const __attribute__((address_space(1))) unsigned int*)g,
      (__attribute__((address_space(3))) unsigned int*)l, 16, 0, 0);
}

// ---------------- Fused prep: rope table + X cvt + Wqkv transpose -----------
__global__ __launch_bounds__(256) void k_prep(
    const float* __restrict__ X,  const float* __restrict__ Wq,
    const float* __restrict__ Wk, const float* __restrict__ Wv,
    float* __restrict__ ct, float* __restrict__ st,
    unsigned short* __restrict__ Xb, unsigned short* __restrict__ Wt)
{
  __shared__ float t[32][33];
  int bid = blockIdx.x;
  if (bid < 128){                       // rope cos/sin table
    int i = bid*256 + threadIdx.x;
    int tt = i >> 5, f = i & 31;
    float freq = powf(10000.0f, -(float)f/32.0f);
    float a = (float)tt * freq;
    ct[i] = cosf(a); st[i] = sinf(a);
    return;
  }
  bid -= 128;
  if (bid < 1024){                      // X fp32 -> bf16
    const int n4 = 2048*2048/4;
    for (int i = bid*256 + threadIdx.x; i < n4; i += 1024*256){
      float4 v = ((const float4*)X)[i];
      ushort4 o; o.x=f2b(v.x); o.y=f2b(v.y); o.z=f2b(v.z); o.w=f2b(v.w);
      ((ushort4*)Xb)[i] = o;
    }
    return;
  }
  bid -= 1024;
  {                                     // W[K][N] -> Wt[N][K] (Q|K|V fused)
    int bx = bid % 96, by = bid / 96;
    int n0 = bx*32, k0 = by*32;
    const float* src; int N, nl;
    if (n0 < 2048)      { src=Wq; N=2048; nl=n0; }
    else if (n0 < 2560) { src=Wk; N=512;  nl=n0-2048; }
    else                { src=Wv; N=512;  nl=n0-2560; }
    int r = threadIdx.x>>5, c = threadIdx.x&31;
    #pragma unroll
    for (int it=0; it<4; ++it)
      t[r+8*it][c] = src[(size_t)(k0+r+8*it)*N + nl + c];
    __syncthreads();
    #pragma unroll
    for (int it=0; it<4; ++it)
      Wt[(size_t)(n0+r+8*it)*2048 + k0 + c] = f2b(t[c][r+8*it]);
  }
}

// ---------------- QKV GEMM: 128x64 tile, BK=32, 3-buffer vmcnt(3) -----------
// grid 768 = 3 blocks/CU. XCD x owns n-tiles [6x,6x+6) -> weight slice 1.5MB
// L2-resident. q pre-scaled by 0.125*log2(e); v written transposed.
// Tile-size optimum confirmed both ways: 128x128 (R13) and 64x64 (R16) both
// slower -- this kernel is LDS-throughput-bound at 0.75 ds_read/MFMA.
__global__ __launch_bounds__(256) void k_qkv(
    const unsigned short* __restrict__ A, const unsigned short* __restrict__ Bt,
    const float* __restrict__ ct, const float* __restrict__ st,
    unsigned short* __restrict__ qb, unsigned short* __restrict__ kb,
    unsigned short* __restrict__ vt)
{
  __shared__ unsigned short As[3][128*32];
  __shared__ unsigned short Bs[3][64*32];
  const int xcd = blockIdx.x & 7, idx = blockIdx.x >> 3;
  const int mt = idx & 15;
  const int nt = xcd*6 + (idx >> 4);    // 0..47
  const int bm = mt*128, bn_g = nt*64;
  const int tid=threadIdx.x, wave=tid>>6, lane=tid&63;
  const int lrow=lane&15, kgrp=lane>>4;
  const int wm=(wave>>1)*64, wn=(wave&1)*32;
  const int arow = tid>>2;
  const int acs  = (((tid&3) ^ ((tid>>3)&3)))*8;   // pre-swizzled global 16B-slot
  const int ksw  = (kgrp ^ ((lrow>>1)&3))*8;       // swizzled read slot
  f32x4 acc[4][2] = {};

  #define STAGE_Q(buf, k0) do {                                                               \
    gload16(&A [(size_t)(bm + arow     )*2048 + (k0) + acs], &As[buf][(wave*64)*8]);          \
    gload16(&A [(size_t)(bm + 64 + arow)*2048 + (k0) + acs], &As[buf][(256 + wave*64)*8]);    \
    gload16(&Bt[(size_t)(bn_g + arow   )*2048 + (k0) + acs], &Bs[buf][(wave*64)*8]);          \
  } while(0)

  #define COMPUTE_Q(buf) do {                                          \
    bf16x8 a0,a1,a2,a3,b0,b1;                                          \
    a0 = *(const bf16x8*)&As[buf][(wm+ 0+lrow)*32 + ksw];              \
    a1 = *(const bf16x8*)&As[buf][(wm+16+lrow)*32 + ksw];              \
    a2 = *(const bf16x8*)&As[buf][(wm+32+lrow)*32 + ksw];              \
    a3 = *(const bf16x8*)&As[buf][(wm+48+lrow)*32 + ksw];              \
    b0 = *(const bf16x8*)&Bs[buf][(wn+ 0+lrow)*32 + ksw];              \
    b1 = *(const bf16x8*)&Bs[buf][(wn+16+lrow)*32 + ksw];              \
    acc[0][0]=MFMA16(a0,b0,acc[0][0]); acc[0][1]=MFMA16(a0,b1,acc[0][1]); \
    acc[1][0]=MFMA16(a1,b0,acc[1][0]); acc[1][1]=MFMA16(a1,b1,acc[1][1]); \
    acc[2][0]=MFMA16(a2,b0,acc[2][0]); acc[2][1]=MFMA16(a2,b1,acc[2][1]); \
    acc[3][0]=MFMA16(a3,b0,acc[3][0]); acc[3][1]=MFMA16(a3,b1,acc[3][1]); \
  } while(0)

  STAGE_Q(0, 0);
  STAGE_Q(1, 32);
  int cur = 0;
  #pragma unroll 1
  for (int t=0; t<64; ++t){
    asm volatile("s_waitcnt vmcnt(3)" ::: "memory");
    __builtin_amdgcn_s_barrier();
    int kn = t+2; if (kn > 63) kn = 63;          // clamped dup loads at tail (unused)
    int nb = cur+2; if (nb > 2) nb -= 3;
    STAGE_Q(nb, kn*32);
    COMPUTE_Q(cur);
    cur = (cur==2) ? 0 : cur+1;
  }

  const int wtype = (bn_g < 2048) ? 0 : (bn_g < 2560 ? 1 : 2);
  const float qscale = 0.125f * 1.44269504f;   // 1/sqrt(D) * log2(e)
  #pragma unroll
  for (int mi=0;mi<4;mi++){
    #pragma unroll
    for (int ni=0;ni<2;ni++){
      int gr0 = bm + wm + mi*16 + kgrp*4;
      int gc  = bn_g + wn + ni*16 + lrow;
      if (wtype==2){
        int c = gc - 2560;                 // d_global in [0,512)
        int bq = gr0 >> 10, s0 = gr0 & 1023;
        ushort4 o;
        o.x=f2b(acc[mi][ni][0]); o.y=f2b(acc[mi][ni][1]);
        o.z=f2b(acc[mi][ni][2]); o.w=f2b(acc[mi][ni][3]);
        *(ushort4*)&vt[((size_t)(bq*512 + c))*1024 + s0] = o;
      } else {
        int d = gc & 63, fi = d >> 1, odd = d & 1;
        #pragma unroll
        for (int r=0;r<4;r++){
          float x = acc[mi][ni][r];
          float p = __shfl_xor(x, 1, 64);
          int srow = (gr0 + r) & 1023;
          float c = ct[srow*32 + fi], sn = st[srow*32 + fi];
          float o = odd ? (x*c + p*sn) : (x*c - p*sn);
          if (wtype==0) qb[(size_t)(gr0+r)*2048 + gc] = f2b(o*qscale);
          else          kb[(size_t)(gr0+r)*512 + (gc-2048)] = f2b(o);
        }
      }
    }
  }
  #undef STAGE_Q
  #undef COMPUTE_Q
}

// ---------------- Flash attention (GQA, causal) + fused Wo transpose --------
#define LDP 72   // 144B row pitch: 16B-aligned; b128 reads uniform 8/bank
__global__ __launch_bounds__(256) void k_attn(
    const unsigned short* __restrict__ qb, const unsigned short* __restrict__ kb,
    const unsigned short* __restrict__ vt, unsigned short* __restrict__ ctxb,
    const float* __restrict__ Wo, unsigned short* __restrict__ Wot)
{
  __shared__ unsigned short Ks[2][64*LDP];
  __shared__ unsigned short Vs[2][64*LDP];   // V^T rows: [d][kv]
  __shared__ unsigned short QP[64*LDP];      // Q tile, then per-wave P [q][kv]

  if (blockIdx.x >= 512){                    // ---- Wo transpose rider ----
    __shared__ float t[32][33];
    int bid = blockIdx.x - 512;
    int n0 = (bid & 63)*32, k0 = (bid >> 6)*32;
    int r = threadIdx.x>>5, c = threadIdx.x&31;
    #pragma unroll
    for (int it=0; it<4; ++it)
      t[r+8*it][c] = Wo[(size_t)(k0+r+8*it)*2048 + n0 + c];
    __syncthreads();
    #pragma unroll
    for (int it=0; it<4; ++it)
      Wot[(size_t)(n0+r+8*it)*2048 + k0 + c] = f2b(t[c][r+8*it]);
    return;
  }

  const int kvh = blockIdx.x & 7;
  const int s   = blockIdx.x >> 3;           // 0..63
  const int b   = s >> 5;
  const int hh  = (s >> 3) & 3;
  const int p   = s & 7;
  const int h   = kvh*4 + hh;

  const int tid=threadIdx.x, wave=tid>>6, lane=tid&63;
  const int lrow=lane&15, kgrp=lane>>4;
  const int wq = wave*16;
  const int sr = tid>>2, seg = (tid&3)*16;

  const unsigned short* kbase = kb + (size_t)(b*1024)*512 + kvh*64 + seg;
  const unsigned short* vbase = vt + ((size_t)(b*512 + kvh*64 + sr))*1024 + seg;

  #pragma unroll
  for (int phase=0; phase<2; ++phase){
    const int qt = phase==0 ? 15-p : p;
    const int q0 = qt*64;

    __syncthreads();   // all waves done with previous phase's LDS
    { // stage Q tile 64x64 + KV tile j=0 into buf 0
      const unsigned short* src = qb + (size_t)(b*1024 + q0 + sr)*2048 + h*64 + seg;
      *(uint4*)&QP[sr*LDP + seg]     = *(const uint4*)&src[0];
      *(uint4*)&QP[sr*LDP + seg + 8] = *(const uint4*)&src[8];
      const unsigned short* ksrc = kbase + (size_t)sr*512;
      *(uint4*)&Ks[0][sr*LDP + seg]     = *(const uint4*)&ksrc[0];
      *(uint4*)&Ks[0][sr*LDP + seg + 8] = *(const uint4*)&ksrc[8];
      *(uint4*)&Vs[0][sr*LDP + seg]     = *(const uint4*)&vbase[0];
      *(uint4*)&Vs[0][sr*LDP + seg + 8] = *(const uint4*)&vbase[8];
    }
    __syncthreads();

    bf16x8 qa[2];
    #pragma unroll
    for (int ks=0;ks<2;ks++)
      qa[ks] = *(const bf16x8*)&QP[(wq+lrow)*LDP + ks*32 + kgrp*8];

    float m_run = -1e30f, l_run = 0.f;
    f32x4 out[4] = {};

    for (int j=0;j<=qt;j++){
      const int cb = j&1;
      uint4 kra, krb, vra, vrb;
      if (j < qt){   // T14: issue next tile's loads; latency hides under compute
        const unsigned short* ksrc = kbase + (size_t)((j+1)*64 + sr)*512;
        kra = *(const uint4*)&ksrc[0]; krb = *(const uint4*)&ksrc[8];
        const unsigned short* vsrc = vbase + (j+1)*64;
        vra = *(const uint4*)&vsrc[0]; vrb = *(const uint4*)&vsrc[8];
      }

      // S^T = K·Q^T (exp2 domain): sc[ni][r] = S[q=wq+lrow][kv=ni*16+kgrp*4+r]
      f32x4 sc[4] = {};
      __builtin_amdgcn_s_setprio(1);
      #pragma unroll
      for (int ks=0;ks<2;ks++){
        #pragma unroll
        for (int ni=0;ni<4;ni++){
          bf16x8 kf = *(const bf16x8*)&Ks[cb][(ni*16+lrow)*LDP + ks*32 + kgrp*8];
          sc[ni] = MFMA16(kf, qa[ks], sc[ni]);
        }
      }
      __builtin_amdgcn_s_setprio(0);

      if (j == qt){   // causal mask: kv_local > q_local
        #pragma unroll
        for (int ni=0;ni<4;ni++)
          #pragma unroll
          for (int r=0;r<4;r++)
            if (ni*16 + kgrp*4 + r > wq + lrow) sc[ni][r] = -1e30f;
      }

      // online softmax: in-lane over 16 scores, + 2 shfl across sibling lanes.
      float mx = sc[0][0];
      #pragma unroll
      for (int ni=0;ni<4;ni++)
        #pragma unroll
        for (int r=0;r<4;r++) mx = fmaxf(mx, sc[ni][r]);
      mx = fmaxf(mx, __shfl_xor(mx, 16, 64));
      mx = fmaxf(mx, __shfl_xor(mx, 32, 64));
      // defer-max (T13): only rescale when max grew by >12 (log2 domain)
      if (__any(mx > m_run + 12.0f)){
        float mnew = fmaxf(m_run, mx);
        float corr = exp2f(m_run - mnew);
        m_run = mnew;
        l_run *= corr;
        #pragma unroll
        for (int di=0;di<4;di++)
          #pragma unroll
          for (int r=0;r<4;r++) out[di][r] *= corr;
      }
      float rsum = 0.f;
      #pragma unroll
      for (int ni=0;ni<4;ni++)
        #pragma unroll
        for (int r=0;r<4;r++){
          float pv = exp2f(sc[ni][r] - m_run);
          sc[ni][r] = pv;
          rsum += pv;
        }
      rsum += __shfl_xor(rsum, 16, 64);
      rsum += __shfl_xor(rsum, 32, 64);
      l_run += rsum;

      // P[q][kv] -> wave-private QP rows; 4x b64 writes (no barrier needed)
      #pragma unroll
      for (int ni=0;ni<4;ni++){
        ushort4 o;
        o.x=f2b(sc[ni][0]); o.y=f2b(sc[ni][1]);
        o.z=f2b(sc[ni][2]); o.w=f2b(sc[ni][3]);
        *(ushort4*)&QP[(wq+lrow)*LDP + ni*16 + kgrp*4] = o;
      }

      // O^T += V^T · P
      __builtin_amdgcn_s_setprio(1);
      #pragma unroll
      for (int ks2=0;ks2<2;ks2++){
        bf16x8 pb = *(const bf16x8*)&QP[(wq+lrow)*LDP + ks2*32 + kgrp*8];
        #pragma unroll
        for (int di=0;di<4;di++){
          bf16x8 vf = *(const bf16x8*)&Vs[cb][(di*16+lrow)*LDP + ks2*32 + kgrp*8];
          out[di] = MFMA16(vf, pb, out[di]);
        }
      }
      __builtin_amdgcn_s_setprio(0);

      if (j < qt){   // write next tile into buf (j+1)&1
        const int nb = (j+1)&1;
        *(uint4*)&Ks[nb][sr*LDP + seg]     = kra;
        *(uint4*)&Ks[nb][sr*LDP + seg + 8] = krb;
        *(uint4*)&Vs[nb][sr*LDP + seg]     = vra;
        *(uint4*)&Vs[nb][sr*LDP + seg + 8] = vrb;
      }
      __syncthreads();
    }

    // out[di][r] = O[q = wq+lrow][d = di*16+kgrp*4+r] -> 4x ushort4 stores
    float rl = 1.0f / l_run;
    #pragma unroll
    for (int di=0;di<4;di++){
      ushort4 o;
      o.x=f2b(out[di][0]*rl); o.y=f2b(out[di][1]*rl);
      o.z=f2b(out[di][2]*rl); o.w=f2b(out[di][3]*rl);
      *(ushort4*)&ctxb[(size_t)(b*1024 + q0 + wq + lrow)*2048
                       + h*64 + di*16 + kgrp*4] = o;
    }
  }
}

// ---------------- Output projection: 64x64 tile, BK=32, 3-buffer vmcnt(2) ---
// grid 1024 (32 mt x 32 nt) = 4 blocks/CU, 16 waves/CU. XCD x owns n-tiles
// [4x,4x+4) -> Wot slice 1MB in L2. Wave grid 2x2, each wave 32x32.
__global__ __launch_bounds__(256) void k_oproj(
    const unsigned short* __restrict__ A, const unsigned short* __restrict__ Bt,
    float* __restrict__ out)
{
  __shared__ unsigned short As[3][64*32];
  __shared__ unsigned short Bs[3][64*32];
  const int xcd = blockIdx.x & 7, idx = blockIdx.x >> 3;   // idx 0..127
  const int mt = idx & 31;
  const int nt = xcd*4 + (idx >> 5);    // 0..31
  const int bm = mt*64, bn = nt*64;
  const int tid=threadIdx.x, wave=tid>>6, lane=tid&63;
  const int lrow=lane&15, kgrp=lane>>4;
  const int wm=(wave>>1)*32, wn=(wave&1)*32;
  const int arow = tid>>2;
  const int acs  = (((tid&3) ^ ((tid>>3)&3)))*8;
  const int ksw  = (kgrp ^ ((lrow>>1)&3))*8;
  f32x4 acc[2][2] = {};

  #define STAGE_O(buf, k0) do {                                                               \
    gload16(&A [(size_t)(bm + arow)*2048 + (k0) + acs], &As[buf][(wave*64)*8]);               \
    gload16(&Bt[(size_t)(bn + arow)*2048 + (k0) + acs], &Bs[buf][(wave*64)*8]);               \
  } while(0)

  #define COMPUTE_O(buf) do {                                          \
    bf16x8 a0,a1,b0,b1;                                                \
    a0 = *(const bf16x8*)&As[buf][(wm+ 0+lrow)*32 + ksw];              \
    a1 = *(const bf16x8*)&As[buf][(wm+16+lrow)*32 + ksw];              \
    b0 = *(const bf16x8*)&Bs[buf][(wn+ 0+lrow)*32 + ksw];              \
    b1 = *(const bf16x8*)&Bs[buf][(wn+16+lrow)*32 + ksw];              \
    acc[0][0]=MFMA16(a0,b0,acc[0][0]); acc[0][1]=MFMA16(a0,b1,acc[0][1]); \
    acc[1][0]=MFMA16(a1,b0,acc[1][0]); acc[1][1]=MFMA16(a1,b1,acc[1][1]); \
  } while(0)

  STAGE_O(0, 0);
  STAGE_O(1, 32);
  int cur = 0;
  #pragma unroll 1
  for (int t=0; t<64; ++t){
    asm volatile("s_waitcnt vmcnt(2)" ::: "memory");
    __builtin_amdgcn_s_barrier();
    int kn = t+2; if (kn > 63) kn = 63;
    int nb = cur+2; if (nb > 2) nb -= 3;
    STAGE_O(nb, kn*32);
    COMPUTE_O(cur);
    cur = (cur==2) ? 0 : cur+1;
  }

  #pragma unroll
  for (int mi=0;mi<2;mi++)
    #pragma unroll
    for (int ni=0;ni<2;ni++){
      int gr0 = bm + wm + mi*16 + kgrp*4;
      int gc  = bn + wn + ni*16 + lrow;
      #pragma unroll
      for (int r=0;r<4;r++)
        out[(size_t)(gr0+r)*2048 + gc] = acc[mi][ni][r];
    }
  #undef STAGE_O
  #undef COMPUTE_O
}

// ---------------- launch ----------------------------------------------------
extern "C" void kernel_launch(void* const* d_in, const int* in_sizes, int n_in,
                              void* d_out, int out_size, void* d_ws, size_t ws_size,
                              hipStream_t stream)
{
  const float* X  = (const float*)d_in[0];
  const float* Wq = (const float*)d_in[1];
  const float* Wk = (const float*)d_in[2];
  const float* Wv = (const float*)d_in[3];
  const float* Wo = (const float*)d_in[4];
  float* out = (float*)d_out;
  char* ws = (char*)d_ws;

  const size_t MB = 1048576;
  float* ct = (float*)ws;                                   // 128 KB
  float* st = (float*)(ws + 128*1024);                      // 128 KB
  unsigned short* Xb   = (unsigned short*)(ws + 256*1024);            // 8 MB
  unsigned short* Wt   = (unsigned short*)(ws + 256*1024 + 8*MB);     // 12 MB
  unsigned short* Wot  = (unsigned short*)(ws + 256*1024 + 20*MB);    // 8 MB
  unsigned short* qb   = (unsigned short*)(ws + 256*1024 + 28*MB);    // 8 MB
  unsigned short* kb   = (unsigned short*)(ws + 256*1024 + 36*MB);    // 2 MB
  unsigned short* vt   = (unsigned short*)(ws + 256*1024 + 38*MB);    // 2 MB (V^T)
  unsigned short* ctxb = (unsigned short*)(ws + 256*1024 + 40*MB);    // 8 MB

  hipLaunchKernelGGL(k_prep, dim3(7296), dim3(256), 0, stream,
                     X, Wq, Wk, Wv, ct, st, Xb, Wt);
  hipLaunchKernelGGL(k_qkv, dim3(768), dim3(256), 0, stream,
                     Xb, Wt, ct, st, qb, kb, vt);
  hipLaunchKernelGGL(k_attn, dim3(4608), dim3(256), 0, stream,
                     qb, kb, vt, ctxb, Wo, Wot);
  hipLaunchKernelGGL(k_oproj, dim3(1024), dim3(256), 0, stream, ctxb, Wot, out);
}